// Round 1
// baseline (399.849 us; speedup 1.0000x reference)
//
#include <hip/hip_runtime.h>

#define NBATCH 1024
#define NS     1024
#define NT     32
#define BLK    16
#define LOG2E  1.44269504088896340736f
#define LN2    0.69314718055994530942f

// fast hardware transcendentals (single v_exp_f32 / v_log_f32)
__device__ __forceinline__ float fexp2(float x) { return __builtin_amdgcn_exp2f(x); }
__device__ __forceinline__ float flog2(float x) { return __builtin_amdgcn_logf(x); }

__global__ __launch_bounds__(64) void crf_fused(
    const float* __restrict__ logits,   // [B, S, T]
    const float* __restrict__ trans,    // [T, T]
    const int*   __restrict__ tags,     // [B, S]
    const int*   __restrict__ lens,     // [B]
    float*       __restrict__ out)      // [1]
{
    __shared__ float ldsT[NT * NT];   // raw transitions (for gold score)
    __shared__ float ldsP[64];        // per-step exp(v) exchange

    const int tid  = threadIdx.x;
    const int half = tid >> 5;        // which batch of the pair
    const int j    = tid & 31;        // tag owned by this lane
    const int b    = blockIdx.x * 2 + half;

    // stage raw transitions to LDS (coalesced)
    for (int k2 = tid; k2 < NT * NT; k2 += 64) ldsT[k2] = trans[k2];
    __syncthreads();

    // lane j holds column j of E2 = exp2(trans * log2e) in registers
    float Ecol[NT];
    #pragma unroll
    for (int i = 0; i < NT; i++) Ecol[i] = fexp2(ldsT[i * NT + j] * LOG2E);

    const float* base = logits + (size_t)b * NS * NT;
    const int*   tgp  = tags + b * NS;
    const int    len  = lens[b];

    // state: V = v_rel (base-2 units), off = accumulated offset (base-2)
    float e0    = base[j];                 // t = 0 emission
    float V     = e0 * LOG2E;
    float off   = 0.0f;
    int   tprev = tgp[0];
    float gold  = (j == tprev) ? e0 : 0.0f;   // pos 0 always < len (len >= 1)

    float ebA[BLK], ebB[BLK];
    int   tbA[BLK], tbB[BLK];

    auto loadblk = [&](float (&eb)[BLK], int (&tb)[BLK], int k) {
        const int tbase = k * BLK;
        #pragma unroll
        for (int i = 0; i < BLK; i++) {
            eb[i] = base[(tbase + i) * NT + j];
            tb[i] = tgp[tbase + i];
        }
    };

    auto procblk = [&](float (&eb)[BLK], int (&tb)[BLK], int k) {
        #pragma unroll
        for (int i = 0; i < BLK; i++) {
            const int t = k * BLK + i;
            if (t == 0) continue;            // wave-uniform, only block 0
            // periodic renormalization: bounds exp2 args (drift <= ~76 per 4 steps)
            if ((t & 3) == 1) {
                float m = V;
                #pragma unroll
                for (int d = 16; d; d >>= 1) m = fmaxf(m, __shfl_xor(m, d, 32));
                V   -= m;
                off += m;
            }
            ldsP[tid] = fexp2(V);
            __syncthreads();
            // s[j] = sum_i p[i] * E[i][j] ; broadcast reads, E in registers
            const float4* pv = (const float4*)(ldsP + half * NT);
            float a0 = 0.f, a1 = 0.f, a2 = 0.f, a3 = 0.f;
            #pragma unroll
            for (int q = 0; q < 8; q++) {
                float4 P = pv[q];
                a0 = fmaf(P.x, Ecol[4*q+0], a0);
                a1 = fmaf(P.y, Ecol[4*q+1], a1);
                a2 = fmaf(P.z, Ecol[4*q+2], a2);
                a3 = fmaf(P.w, Ecol[4*q+3], a3);
            }
            const float e  = eb[i];
            const int   tc = tb[i];
            V = flog2((a0 + a1) + (a2 + a3)) + e * LOG2E;
            // fused gold score: exactly lane j == tc contributes
            const float tr = ldsT[tprev * NT + tc];
            gold += ((t < len) & (j == tc)) ? (e + tr) : 0.0f;
            tprev = tc;
            // no trailing barrier needed: single-wave block, DS pipe is
            // in-order per wave, so this iteration's reads complete before
            // the next iteration's ldsP write.
        }
    };

    // steps t = 1..1023 in 64 blocks of 16, double-buffered prefetch
    loadblk(ebA, tbA, 0);
    for (int k = 0; k < 64; k += 2) {
        loadblk(ebB, tbB, k + 1);
        procblk(ebA, tbA, k);
        if (k + 2 < 64) loadblk(ebA, tbA, k + 2);
        procblk(ebB, tbB, k + 1);
    }

    // finalize: log_z = ln2 * (off + lse2(V)) ; reduce gold over tags
    float m = V;
    #pragma unroll
    for (int d = 16; d; d >>= 1) m = fmaxf(m, __shfl_xor(m, d, 32));
    float se = fexp2(V - m);
    float gs = gold;
    #pragma unroll
    for (int d = 16; d; d >>= 1) {
        se += __shfl_xor(se, d, 32);
        gs += __shfl_xor(gs, d, 32);
    }
    if (j == 0) {
        const float log_z = (off + m + flog2(se)) * LN2;
        atomicAdd(out, (log_z - gs) * (1.0f / (float)NBATCH));
    }
}

extern "C" void kernel_launch(void* const* d_in, const int* in_sizes, int n_in,
                              void* d_out, int out_size, void* d_ws, size_t ws_size,
                              hipStream_t stream) {
    const float* logits = (const float*)d_in[0];
    const float* trans  = (const float*)d_in[1];
    const int*   tags   = (const int*)d_in[2];
    const int*   lens   = (const int*)d_in[3];

    hipMemsetAsync(d_out, 0, sizeof(float), stream);
    crf_fused<<<dim3(NBATCH / 2), dim3(64), 0, stream>>>(
        logits, trans, tags, lens, (float*)d_out);
}

// Round 2
// 290.940 us; speedup vs baseline: 1.3743x; 1.3743x over previous
//
#include <hip/hip_runtime.h>

#define NB 1024
#define NS 1024
#define NT 32
#define L2E 1.44269504088896340736f
#define LN2 0.69314718055994530942f

typedef short        bfrag  __attribute__((ext_vector_type(8)));   // 8 bf16 (4 VGPR)
typedef float        cfrag  __attribute__((ext_vector_type(16)));  // 16 f32 acc
typedef __bf16       bf16x2 __attribute__((ext_vector_type(2)));
typedef float        f32x8  __attribute__((ext_vector_type(8)));
typedef float        f32x2  __attribute__((ext_vector_type(2)));
typedef unsigned int u32;
typedef unsigned int u32x4  __attribute__((ext_vector_type(4)));

__device__ __forceinline__ float fexp2(float x){ return __builtin_amdgcn_exp2f(x); }
__device__ __forceinline__ float flog2(float x){ return __builtin_amdgcn_logf(x); }
__device__ __forceinline__ float frcp (float x){ return __builtin_amdgcn_rcpf(x); }

__device__ __forceinline__ u32 pkbf(float a, float b){
    f32x2 t; t.x = a; t.y = b;
    return __builtin_bit_cast(u32, __builtin_convertvector(t, bf16x2));  // RNE pack
}
__device__ __forceinline__ bfrag mk_afrag(f32x8 v){
    u32x4 r;
    r[0] = pkbf(v[0], v[1]); r[1] = pkbf(v[2], v[3]);
    r[2] = pkbf(v[4], v[5]); r[3] = pkbf(v[6], v[7]);
    return __builtin_bit_cast(bfrag, r);
}

// ---------------- Phase 1: per-(batch,chunk) 32x32 transfer matrix ----------------
// MT ← (D_t E^T) @ MT, 128 steps. MT kept as bf16 B-operand frags; per-COLUMN renorm.
__global__ __launch_bounds__(64, 4) void crf_chunk(
    const float* __restrict__ logits, const float* __restrict__ trans,
    const int* __restrict__ tags, const int* __restrict__ lens,
    u32* __restrict__ wmat, float* __restrict__ woff, float* __restrict__ wgold)
{
    const int tid = threadIdx.x;
    const int m = tid & 31, h = tid >> 5;
    const int bc = blockIdx.x;
    const int b = bc >> 3, c = bc & 7;

    const float* base = logits + (size_t)b * NS * NT;
    const int*   tgp  = tags + b * NS;
    const int    len  = lens[b];

    // A-operand base: Et[m][k] = exp(trans[k][m]); lane m=lane&31, k = 16f + 8h + j
    f32x8 Et0, Et1;
    #pragma unroll
    for (int j = 0; j < 8; j++){
        Et0[j] = fexp2(L2E * trans[(     8*h + j)*NT + m]);
        Et1[j] = fexp2(L2E * trans[(16 + 8*h + j)*NT + m]);
    }

    // B = identity (packed bf16): B[k][n], n=lane&31, dword d covers k = 16f+8h+2d(+1)
    u32x4 B0v, B1v;
    #pragma unroll
    for (int d = 0; d < 4; d++){
        int k0 = 8*h + 2*d;      u32 v = 0;
        if (k0     == m) v |= 0x3F80u;
        if (k0 + 1 == m) v |= 0x3F800000u;
        B0v[d] = v;
        int k1 = 16 + 8*h + 2*d; v = 0;
        if (k1     == m) v |= 0x3F80u;
        if (k1 + 1 == m) v |= 0x3F800000u;
        B1v[d] = v;
    }

    cfrag zacc;
    #pragma unroll
    for (int q = 0; q < 16; q++) zacc[q] = 0.0f;

    float off = 0.0f;      // per-column (col = m) accumulated log2 scale
    float gold = 0.0f;     // emission part of gold score
    if (c == 0){
        float e0 = base[m];
        int  tag0 = tgp[0];
        gold += (h == 0 && m == tag0) ? e0 : 0.0f;   // t=0 always < len (len>=1)
    }

    const int tbeg = c*128 + 1;
    const int tend = (c == 7) ? (NS - 1) : (c*128 + 128);   // inclusive
    const int L    = tend - tbeg + 1;                       // 128 (127 for c==7)

    float eA[8], eB[8]; int gA[8], gB[8];
    auto loadblk = [&](float (&e)[8], int (&g)[8], int k){
        #pragma unroll
        for (int i = 0; i < 8; i++){
            int t = tbeg + k*8 + i;
            t = t > (NS-1) ? (NS-1) : t;      // clamp (c==7 tail), dup loads unused
            e[i] = base[t*NT + m];
            g[i] = tgp[t];
        }
    };

    auto step = [&](float e, int tagc, int t, bool renorm){
        float d = fexp2(e * L2E);
        bfrag A0 = mk_afrag(Et0 * d);
        bfrag A1 = mk_afrag(Et1 * d);
        cfrag acc = __builtin_amdgcn_mfma_f32_32x32x16_bf16(
                        A0, __builtin_bit_cast(bfrag, B0v), zacc, 0, 0, 0);
        acc = __builtin_amdgcn_mfma_f32_32x32x16_bf16(
                        A1, __builtin_bit_cast(bfrag, B1v), acc, 0, 0, 0);

        gold += (h == 0 && m == tagc && t < len) ? e : 0.0f;

        // pack new MT (C/D layout) to bf16; per-column renorm every 4 steps
        u32 P[8];
        if (renorm){
            float mx = acc[0];
            #pragma unroll
            for (int q = 1; q < 16; q++) mx = fmaxf(mx, acc[q]);
            mx = fmaxf(mx, __shfl_xor(mx, 32, 64));   // column spans lanes m, m+32
            off += flog2(mx);
            float s = frcp(mx);
            #pragma unroll
            for (int i = 0; i < 8; i++) P[i] = pkbf(acc[2*i]*s, acc[2*i+1]*s);
        } else {
            #pragma unroll
            for (int i = 0; i < 8; i++) P[i] = pkbf(acc[2*i], acc[2*i+1]);
        }

        // C/D → B-operand: exchange row-half quads with lane^32
        u32 X0 = __shfl_xor(h ? P[0] : P[2], 32, 64);
        u32 X1 = __shfl_xor(h ? P[1] : P[3], 32, 64);
        u32 X2 = __shfl_xor(h ? P[4] : P[6], 32, 64);
        u32 X3 = __shfl_xor(h ? P[5] : P[7], 32, 64);
        B0v[0] = h ? X0 : P[0];  B0v[1] = h ? X1 : P[1];
        B0v[2] = h ? P[2] : X0;  B0v[3] = h ? P[3] : X1;
        B1v[0] = h ? X2 : P[4];  B1v[1] = h ? X3 : P[5];
        B1v[2] = h ? P[6] : X2;  B1v[3] = h ? P[7] : X3;
    };

    loadblk(eA, gA, 0);
    const int nblk = 16;
    for (int k = 0; k < nblk; k += 2){
        loadblk(eB, gB, k + 1);
        {
            #pragma unroll
            for (int i = 0; i < 8; i++)
                step(eA[i], gA[i], tbeg + k*8 + i, (i & 3) == 3);   // even blocks always full
        }
        if (k + 2 < nblk) loadblk(eA, gA, k + 2);
        {
            const int nst = (L - (k+1)*8) >= 8 ? 8 : (L - (k+1)*8); // 8, or 7 on c==7 tail
            #pragma unroll
            for (int i = 0; i < 8; i++)
                if (i < nst) step(eB[i], gB[i], tbeg + (k+1)*8 + i, (i & 3) == 3);
        }
    }

    // store MT in B-frag form: wmat[bc*512 + d*64 + lane]
    const size_t mb = (size_t)bc * 512;
    #pragma unroll
    for (int d = 0; d < 4; d++){
        wmat[mb + d*64 + tid]     = B0v[d];
        wmat[mb + (4+d)*64 + tid] = B1v[d];
    }
    if (h == 0) woff[bc*32 + m] = off;

    #pragma unroll
    for (int d = 1; d <= 16; d <<= 1) gold += __shfl_xor(gold, d, 64);
    if (tid == 0) wgold[bc] = gold;
}

// ---------------- Phase 2: per-batch combine + gold transitions ----------------
__global__ __launch_bounds__(64) void crf_combine(
    const float* __restrict__ logits, const float* __restrict__ trans,
    const int* __restrict__ tags, const int* __restrict__ lens,
    const u32* __restrict__ wmat, const float* __restrict__ woff,
    const float* __restrict__ wgold, float* __restrict__ out)
{
    __shared__ __align__(16) float ldsT[NT*NT];
    __shared__ __align__(16) int   ldsTag[NS];
    __shared__ __align__(16) float ldsU[NT];

    const int tid = threadIdx.x;
    const int m   = tid & 31;
    const int b   = blockIdx.x;
    const int len = lens[b];

    #pragma unroll
    for (int i = 0; i < 16; i++) ldsT[tid + i*64] = trans[tid + i*64];
    const int4* tg4 = (const int4*)(tags + b*NS);
    #pragma unroll
    for (int i = 0; i < 4; i++) ((int4*)ldsTag)[tid + i*64] = tg4[tid + i*64];
    __syncthreads();

    // gold transition part
    float g = 0.0f;
    #pragma unroll
    for (int it = 0; it < 16; it++){
        int t = 1 + tid + it*64;
        if (t < NS && t < len)
            g += ldsT[ldsTag[t-1]*NT + ldsTag[t]];
    }
    if (tid < 8) g += wgold[b*8 + tid];

    // v init = exp(emit_0), combine 8 chunk matrices in log-scaled space
    float v = fexp2(L2E * logits[(size_t)b*NS*NT + m]);
    float voff = 0.0f;

    const int n  = m;                       // output tag owned by this lane
    const int f  = n >> 4;
    const int hh = (n >> 3) & 1;
    const int di = f*4 + ((n >> 1) & 3);    // stored dword index holding row k=n

    for (int cc = 0; cc < 8; cc++){
        const int bcn = b*8 + cc;
        float offm = woff[bcn*32 + m];
        float w = flog2(v) + offm;          // per-element log2 magnitude
        float mw = w;
        #pragma unroll
        for (int d = 1; d <= 16; d <<= 1) mw = fmaxf(mw, __shfl_xor(mw, d, 64));
        float u = fexp2(w - mw);
        if (tid < 32) ldsU[m] = u;
        __syncthreads();

        const uint4*  mp = (const uint4*)(wmat + (size_t)bcn*512 + di*64 + hh*32);
        float acc = 0.0f;
        #pragma unroll
        for (int qq = 0; qq < 8; qq++){
            uint4  md = mp[qq];
            float4 uu = ((const float4*)ldsU)[qq];
            float e0 = __builtin_bit_cast(float, (n&1) ? (md.x & 0xFFFF0000u) : (md.x << 16));
            float e1 = __builtin_bit_cast(float, (n&1) ? (md.y & 0xFFFF0000u) : (md.y << 16));
            float e2 = __builtin_bit_cast(float, (n&1) ? (md.z & 0xFFFF0000u) : (md.z << 16));
            float e3 = __builtin_bit_cast(float, (n&1) ? (md.w & 0xFFFF0000u) : (md.w << 16));
            acc = fmaf(e0, uu.x, acc);
            acc = fmaf(e1, uu.y, acc);
            acc = fmaf(e2, uu.z, acc);
            acc = fmaf(e3, uu.w, acc);
        }
        v = acc;
        voff += mw;
        __syncthreads();
    }

    float s = v;
    #pragma unroll
    for (int d = 1; d <= 16; d <<= 1) s += __shfl_xor(s, d, 64);   // sum over 32 tags
    #pragma unroll
    for (int d = 1; d <= 32; d <<= 1) g += __shfl_xor(g, d, 64);   // sum over 64 lanes
    if (tid == 0){
        float logz = LN2 * (voff + flog2(s));
        atomicAdd(out, (logz - g) * (1.0f / (float)NB));
    }
}

extern "C" void kernel_launch(void* const* d_in, const int* in_sizes, int n_in,
                              void* d_out, int out_size, void* d_ws, size_t ws_size,
                              hipStream_t stream) {
    const float* logits = (const float*)d_in[0];
    const float* trans  = (const float*)d_in[1];
    const int*   tags   = (const int*)d_in[2];
    const int*   lens   = (const int*)d_in[3];

    u32*   wmat  = (u32*)d_ws;                       // 8192*512*4 = 16 MB
    float* woff  = (float*)(wmat + 8192*512);        // 8192*32 floats = 1 MB
    float* wgold = woff + 8192*32;                   // 8192 floats

    hipMemsetAsync(d_out, 0, sizeof(float), stream);
    crf_chunk  <<<8192, 64, 0, stream>>>(logits, trans, tags, lens, wmat, woff, wgold);
    crf_combine<<<1024, 64, 0, stream>>>(logits, trans, tags, lens, wmat, woff, wgold,
                                         (float*)d_out);
}

// Round 3
// 272.532 us; speedup vs baseline: 1.4672x; 1.0675x over previous
//
#include <hip/hip_runtime.h>

#define NB 1024
#define NS 1024
#define NT 32
#define L2E 1.44269504088896340736f
#define LN2 0.69314718055994530942f

typedef short        bfrag  __attribute__((ext_vector_type(8)));   // 8 bf16 (4 VGPR)
typedef float        cfrag  __attribute__((ext_vector_type(16)));  // 16 f32 acc
typedef __bf16       bf16x2 __attribute__((ext_vector_type(2)));
typedef float        f32x8  __attribute__((ext_vector_type(8)));
typedef float        f32x2  __attribute__((ext_vector_type(2)));
typedef unsigned int u32;
typedef unsigned int u32x2v __attribute__((ext_vector_type(2)));
typedef unsigned int u32x4  __attribute__((ext_vector_type(4)));

__device__ __forceinline__ float fexp2(float x){ return __builtin_amdgcn_exp2f(x); }
__device__ __forceinline__ float flog2(float x){ return __builtin_amdgcn_logf(x); }
__device__ __forceinline__ float frcp (float x){ return __builtin_amdgcn_rcpf(x); }

__device__ __forceinline__ u32 pkbf(float a, float b){
    f32x2 t; t.x = a; t.y = b;
    return __builtin_bit_cast(u32, __builtin_convertvector(t, bf16x2));  // RNE pack
}
__device__ __forceinline__ bfrag mk_afrag(f32x8 v){
    u32x4 r;
    r[0] = pkbf(v[0], v[1]); r[1] = pkbf(v[2], v[3]);
    r[2] = pkbf(v[4], v[5]); r[3] = pkbf(v[6], v[7]);
    return __builtin_bit_cast(bfrag, r);
}

#if __has_builtin(__builtin_amdgcn_permlane32_swap)
#define HAVE_PLSWAP 1
#else
#define HAVE_PLSWAP 0
#endif

// exchange: x stays on its low-half owner, y's low half moves to x's high half, etc.
// After call (per derivation verified against R2's shfl/cndmask mapping):
//   x_new = {x.lanes0-31, y.lanes0-31},  y_new = {x.lanes32-63, y.lanes32-63}
__device__ __forceinline__ void half_swap(u32 &x, u32 &y, int h){
#if HAVE_PLSWAP
    u32x2v r = __builtin_amdgcn_permlane32_swap(x, y, false, false);
    x = r[0]; y = r[1];
#else
    u32 X  = __shfl_xor(h ? x : y, 32, 64);
    u32 nx = h ? X : x;
    u32 ny = h ? y : X;
    x = nx; y = ny;
#endif
}

// ---------------- Phase 1: per-(batch,chunk) 32x32 transfer matrix ----------------
// M <- D_t * (E^T @ M): A-operand (E^T bf16) is CONSTANT; D applied to C/D output
// via broadcast ds_read_b128 of per-row scales staged in LDS. Per-column renorm /4.
__global__ __launch_bounds__(64, 6) void crf_chunk(
    const float* __restrict__ logits, const float* __restrict__ trans,
    const int* __restrict__ tags, const int* __restrict__ lens,
    u32* __restrict__ wmat, float* __restrict__ woff, float* __restrict__ wgold)
{
    __shared__ __align__(16) float dsc[512];   // 2 bufs x 8 steps x 32 rows

    const int tid = threadIdx.x;
    const int m = tid & 31, h = tid >> 5;
    const int bc = blockIdx.x;
    const int b = bc >> 3, c = bc & 7;

    const float* base = logits + (size_t)b * NS * NT;
    const int*   tgp  = tags + b * NS;
    const int    len  = lens[b];

    // constant A frags: Et[m][k] = exp(trans[k][m]); MFMA#1 k=8h+j, MFMA#2 k=16+8h+j
    f32x8 Et0, Et1;
    #pragma unroll
    for (int j = 0; j < 8; j++){
        Et0[j] = fexp2(L2E * trans[(     8*h + j)*NT + m]);
        Et1[j] = fexp2(L2E * trans[(16 + 8*h + j)*NT + m]);
    }
    const bfrag A0f = mk_afrag(Et0);
    const bfrag A1f = mk_afrag(Et1);

    // B = identity (packed bf16): B[k][n], n=lane&31, dword d covers k = 16f+8h+2d(+1)
    u32x4 B0v, B1v;
    #pragma unroll
    for (int d = 0; d < 4; d++){
        int k0 = 8*h + 2*d;      u32 v = 0;
        if (k0     == m) v |= 0x3F80u;
        if (k0 + 1 == m) v |= 0x3F800000u;
        B0v[d] = v;
        int k1 = 16 + 8*h + 2*d; v = 0;
        if (k1     == m) v |= 0x3F80u;
        if (k1 + 1 == m) v |= 0x3F800000u;
        B1v[d] = v;
    }

    cfrag zacc;
    #pragma unroll
    for (int q = 0; q < 16; q++) zacc[q] = 0.0f;

    float off = 0.0f;      // per-column (col = m) accumulated log2 scale
    float gold = 0.0f;     // emission part of gold score
    if (c == 0){
        float e0 = base[m];
        int  tag0 = tgp[0];
        gold += (h == 0 && m == tag0) ? e0 : 0.0f;   // t=0 always < len (len>=1)
    }

    const int tbeg = c*128 + 1;
    const int L    = (c == 7) ? 127 : 128;           // steps in this chunk

    // half h owns steps 4h+0..3 of each 8-step block (halves redundant load/exp2)
    float eA[4], eB[4]; int gA[4], gB[4];

    auto issue = [&](float (&e)[4], int (&g)[4], int k){
        const int t0 = tbeg + k*8 + 4*h;
        #pragma unroll
        for (int i = 0; i < 4; i++){
            int t = t0 + i; t = t > (NS-1) ? (NS-1) : t;   // clamp c==7 tail
            e[i] = base[t*NT + m];
            g[i] = tgp[t];
        }
    };
    auto commit = [&](float (&e)[4], int k){
        float* sp = dsc + (k & 1)*256 + (4*h)*32 + m;
        #pragma unroll
        for (int i = 0; i < 4; i++) sp[i*32] = fexp2(L2E * e[i]);
    };

    auto proc = [&](float (&e)[4], int (&g)[4], int k){
        const float* db = dsc + (k & 1)*256 + 4*h;
        const int rem = L - k*8;
        const int nst = rem >= 8 ? 8 : rem;
        #pragma unroll
        for (int i = 0; i < 8; i++){
            if (i < nst){
                const int t = tbeg + k*8 + i;
                cfrag acc = __builtin_amdgcn_mfma_f32_32x32x16_bf16(
                                A0f, __builtin_bit_cast(bfrag, B0v), zacc, 0, 0, 0);
                acc = __builtin_amdgcn_mfma_f32_32x32x16_bf16(
                                A1f, __builtin_bit_cast(bfrag, B1v), acc, 0, 0, 0);

                // D_t scale: rows per reg-quad are contiguous -> 4 broadcast b128 reads
                float4 d0 = *(const float4*)(db + i*32 +  0);   // rows 4h+0..3
                float4 d1 = *(const float4*)(db + i*32 +  8);   // rows 8+4h+0..3
                float4 d2 = *(const float4*)(db + i*32 + 16);   // rows 16+4h+0..3
                float4 d3 = *(const float4*)(db + i*32 + 24);   // rows 24+4h+0..3
                acc[0]*=d0.x;  acc[1]*=d0.y;  acc[2]*=d0.z;  acc[3]*=d0.w;
                acc[4]*=d1.x;  acc[5]*=d1.y;  acc[6]*=d1.z;  acc[7]*=d1.w;
                acc[8]*=d2.x;  acc[9]*=d2.y;  acc[10]*=d2.z; acc[11]*=d2.w;
                acc[12]*=d3.x; acc[13]*=d3.y; acc[14]*=d3.z; acc[15]*=d3.w;

                // gold emission: owning half has e/tag for this step in reg i&3
                const int li = i & 3;
                if (h == (i >> 2) && m == g[li] && t < len) gold += e[li];

                // per-column renorm every 4 steps
                if ((i & 3) == 3){
                    float mx = acc[0];
                    #pragma unroll
                    for (int q = 1; q < 16; q++) mx = fmaxf(mx, acc[q]);
                    mx = fmaxf(mx, __shfl_xor(mx, 32, 64));
                    off += flog2(mx);
                    float s = frcp(mx);
                    #pragma unroll
                    for (int q = 0; q < 16; q++) acc[q] *= s;
                }

                // pack C/D -> bf16, then half-swap into B-operand layout
                u32 P0 = pkbf(acc[0], acc[1]),  P1 = pkbf(acc[2], acc[3]);
                u32 P2 = pkbf(acc[4], acc[5]),  P3 = pkbf(acc[6], acc[7]);
                u32 P4 = pkbf(acc[8], acc[9]),  P5 = pkbf(acc[10], acc[11]);
                u32 P6 = pkbf(acc[12], acc[13]),P7 = pkbf(acc[14], acc[15]);
                half_swap(P0, P2, h); half_swap(P1, P3, h);
                half_swap(P4, P6, h); half_swap(P5, P7, h);
                B0v[0]=P0; B0v[1]=P1; B0v[2]=P2; B0v[3]=P3;
                B1v[0]=P4; B1v[1]=P5; B1v[2]=P6; B1v[3]=P7;
            }
        }
    };

    issue(eA, gA, 0);
    commit(eA, 0);
    for (int k = 0; k < 16; k += 2){
        issue(eB, gB, k + 1);
        proc(eA, gA, k);
        commit(eB, k + 1);
        if (k + 2 < 16) issue(eA, gA, k + 2);
        proc(eB, gB, k + 1);
        if (k + 2 < 16) commit(eA, k + 2);
    }

    // store MT in B-frag form: wmat[bc*512 + d*64 + lane]
    const size_t mb = (size_t)bc * 512;
    #pragma unroll
    for (int d = 0; d < 4; d++){
        wmat[mb + d*64 + tid]     = B0v[d];
        wmat[mb + (4+d)*64 + tid] = B1v[d];
    }
    if (h == 0) woff[bc*32 + m] = off;

    #pragma unroll
    for (int d = 1; d <= 16; d <<= 1) gold += __shfl_xor(gold, d, 64);
    if (tid == 0) wgold[bc] = gold;
}

// ---------------- Phase 2: per-batch combine + gold transitions ----------------
__global__ __launch_bounds__(64) void crf_combine(
    const float* __restrict__ logits, const float* __restrict__ trans,
    const int* __restrict__ tags, const int* __restrict__ lens,
    const u32* __restrict__ wmat, const float* __restrict__ woff,
    const float* __restrict__ wgold, float* __restrict__ out)
{
    __shared__ __align__(16) float ldsT[NT*NT];
    __shared__ __align__(16) int   ldsTag[NS];
    __shared__ __align__(16) float ldsU[NT];

    const int tid = threadIdx.x;
    const int m   = tid & 31;
    const int b   = blockIdx.x;
    const int len = lens[b];

    #pragma unroll
    for (int i = 0; i < 16; i++) ldsT[tid + i*64] = trans[tid + i*64];
    const int4* tg4 = (const int4*)(tags + b*NS);
    #pragma unroll
    for (int i = 0; i < 4; i++) ((int4*)ldsTag)[tid + i*64] = tg4[tid + i*64];
    __syncthreads();

    // gold transition part
    float g = 0.0f;
    #pragma unroll
    for (int it = 0; it < 16; it++){
        int t = 1 + tid + it*64;
        if (t < NS && t < len)
            g += ldsT[ldsTag[t-1]*NT + ldsTag[t]];
    }
    if (tid < 8) g += wgold[b*8 + tid];

    // v init = exp(emit_0), combine 8 chunk matrices in log-scaled space
    float v = fexp2(L2E * logits[(size_t)b*NS*NT + m]);
    float voff = 0.0f;

    const int n  = m;                       // output tag owned by this lane
    const int f  = n >> 4;
    const int hh = (n >> 3) & 1;
    const int di = f*4 + ((n >> 1) & 3);    // stored dword index holding row k=n

    for (int cc = 0; cc < 8; cc++){
        const int bcn = b*8 + cc;
        float offm = woff[bcn*32 + m];
        float w = flog2(v) + offm;          // per-element log2 magnitude
        float mw = w;
        #pragma unroll
        for (int d = 1; d <= 16; d <<= 1) mw = fmaxf(mw, __shfl_xor(mw, d, 64));
        float u = fexp2(w - mw);
        if (tid < 32) ldsU[m] = u;
        __syncthreads();

        const uint4*  mp = (const uint4*)(wmat + (size_t)bcn*512 + di*64 + hh*32);
        float acc = 0.0f;
        #pragma unroll
        for (int qq = 0; qq < 8; qq++){
            uint4  md = mp[qq];
            float4 uu = ((const float4*)ldsU)[qq];
            float e0 = __builtin_bit_cast(float, (n&1) ? (md.x & 0xFFFF0000u) : (md.x << 16));
            float e1 = __builtin_bit_cast(float, (n&1) ? (md.y & 0xFFFF0000u) : (md.y << 16));
            float e2 = __builtin_bit_cast(float, (n&1) ? (md.z & 0xFFFF0000u) : (md.z << 16));
            float e3 = __builtin_bit_cast(float, (n&1) ? (md.w & 0xFFFF0000u) : (md.w << 16));
            acc = fmaf(e0, uu.x, acc);
            acc = fmaf(e1, uu.y, acc);
            acc = fmaf(e2, uu.z, acc);
            acc = fmaf(e3, uu.w, acc);
        }
        v = acc;
        voff += mw;
        __syncthreads();
    }

    float s = v;
    #pragma unroll
    for (int d = 1; d <= 16; d <<= 1) s += __shfl_xor(s, d, 64);   // sum over 32 tags
    #pragma unroll
    for (int d = 1; d <= 32; d <<= 1) g += __shfl_xor(g, d, 64);   // sum over 64 lanes
    if (tid == 0){
        float logz = LN2 * (voff + flog2(s));
        atomicAdd(out, (logz - g) * (1.0f / (float)NB));
    }
}

extern "C" void kernel_launch(void* const* d_in, const int* in_sizes, int n_in,
                              void* d_out, int out_size, void* d_ws, size_t ws_size,
                              hipStream_t stream) {
    const float* logits = (const float*)d_in[0];
    const float* trans  = (const float*)d_in[1];
    const int*   tags   = (const int*)d_in[2];
    const int*   lens   = (const int*)d_in[3];

    u32*   wmat  = (u32*)d_ws;                       // 8192*512*4 = 16 MB
    float* woff  = (float*)(wmat + 8192*512);        // 8192*32 floats = 1 MB
    float* wgold = woff + 8192*32;                   // 8192 floats

    hipMemsetAsync(d_out, 0, sizeof(float), stream);
    crf_chunk  <<<8192, 64, 0, stream>>>(logits, trans, tags, lens, wmat, woff, wgold);
    crf_combine<<<1024, 64, 0, stream>>>(logits, trans, tags, lens, wmat, woff, wgold,
                                         (float*)d_out);
}

// Round 4
// 266.881 us; speedup vs baseline: 1.4982x; 1.0212x over previous
//
#include <hip/hip_runtime.h>

#define NB 1024
#define NS 1024
#define NT 32
#define L2E 1.44269504088896340736f
#define LN2 0.69314718055994530942f

typedef short        bfrag  __attribute__((ext_vector_type(8)));   // 8 bf16 (4 VGPR)
typedef float        cfrag  __attribute__((ext_vector_type(16)));  // 16 f32 acc
typedef __bf16       bf16x2 __attribute__((ext_vector_type(2)));
typedef float        f32x8  __attribute__((ext_vector_type(8)));
typedef float        f32x2  __attribute__((ext_vector_type(2)));
typedef unsigned int u32;
typedef unsigned int u32x2v __attribute__((ext_vector_type(2)));
typedef unsigned int u32x4  __attribute__((ext_vector_type(4)));

__device__ __forceinline__ float fexp2(float x){ return __builtin_amdgcn_exp2f(x); }
__device__ __forceinline__ float flog2(float x){ return __builtin_amdgcn_logf(x); }

__device__ __forceinline__ u32 pkbf(float a, float b){
    f32x2 t; t.x = a; t.y = b;
    return __builtin_bit_cast(u32, __builtin_convertvector(t, bf16x2));  // RNE pack
}
__device__ __forceinline__ bfrag mk_afrag(f32x8 v){
    u32x4 r;
    r[0] = pkbf(v[0], v[1]); r[1] = pkbf(v[2], v[3]);
    r[2] = pkbf(v[4], v[5]); r[3] = pkbf(v[6], v[7]);
    return __builtin_bit_cast(bfrag, r);
}

#if __has_builtin(__builtin_amdgcn_permlane32_swap)
#define HAVE_PLSWAP 1
#else
#define HAVE_PLSWAP 0
#endif

// after call: x_new = {x.lo32, y.lo32}, y_new = {x.hi32, y.hi32}
__device__ __forceinline__ void half_swap(u32 &x, u32 &y, int h){
#if HAVE_PLSWAP
    u32x2v r = __builtin_amdgcn_permlane32_swap(x, y, false, false);
    x = r[0]; y = r[1];
#else
    u32 X  = __shfl_xor(h ? x : y, 32, 64);
    u32 nx = h ? X : x;
    u32 ny = h ? y : X;
    x = nx; y = ny;
#endif
}

template<int N> struct ic { static constexpr int value = N; };
union accu { cfrag c; f32x2 p[8]; };

// ---------------- Phase 1: per-(batch,chunk) 32x32 transfer matrix ----------------
// 4 independent chunk-waves per 256-thread block (beats the ~16 workgroup/CU cap).
// M <- D_t * (E^T @ M); constant bf16 A; D via broadcast LDS reads; exponent-trick
// renorm every 8 steps (exact power-of-2 scales). Gold score moved to phase 2.
__global__ __launch_bounds__(256, 8) void crf_chunk(
    const float* __restrict__ logits, const float* __restrict__ trans,
    u32* __restrict__ wmat, float* __restrict__ woff)
{
    __shared__ __align__(16) float dscall[4 * 512];   // per-wave: 2 bufs x 8 steps x 32

    const int tid = threadIdx.x;
    const int wv  = tid >> 6, lt = tid & 63;
    const int m   = lt & 31,  h  = lt >> 5;
    const int bc  = blockIdx.x * 4 + wv;
    const int b   = bc >> 3,  c  = bc & 7;
    float* dsc = dscall + wv * 512;

    const float* base = logits + (size_t)b * NS * NT;

    // constant A frags: Et[m][k] = exp(trans[k][m]); MFMA#1 k=8h+j, MFMA#2 k=16+8h+j
    f32x8 Et0, Et1;
    #pragma unroll
    for (int j = 0; j < 8; j++){
        Et0[j] = fexp2(L2E * trans[(     8*h + j)*NT + m]);
        Et1[j] = fexp2(L2E * trans[(16 + 8*h + j)*NT + m]);
    }
    const bfrag A0f = mk_afrag(Et0);
    const bfrag A1f = mk_afrag(Et1);

    // B = identity (packed bf16): B[k][n], n=lane&31, dword d covers k = 16f+8h+2d(+1)
    u32x4 B0v, B1v;
    #pragma unroll
    for (int d = 0; d < 4; d++){
        int k0 = 8*h + 2*d;      u32 v = 0;
        if (k0     == m) v |= 0x3F80u;
        if (k0 + 1 == m) v |= 0x3F800000u;
        B0v[d] = v;
        int k1 = 16 + 8*h + 2*d; v = 0;
        if (k1     == m) v |= 0x3F80u;
        if (k1 + 1 == m) v |= 0x3F800000u;
        B1v[d] = v;
    }

    cfrag zacc;
    #pragma unroll
    for (int q = 0; q < 16; q++) zacc[q] = 0.0f;

    float off = 0.0f;                  // per-column accumulated log2 scale (integer)
    const int tbeg = c*128 + 1;

    float eA[4], eB[4];

    auto issue = [&](float (&e)[4], int k){
        const int t0 = tbeg + k*8 + 4*h;
        #pragma unroll
        for (int i = 0; i < 4; i++){
            int t = t0 + i; t = t > (NS-1) ? (NS-1) : t;   // clamp c==7 tail
            e[i] = base[t*NT + m];
        }
    };
    auto commit = [&](float (&e)[4], int k){
        float* sp = dsc + (k & 1)*256 + (4*h)*32 + m;
        #pragma unroll
        for (int i = 0; i < 4; i++) sp[i*32] = fexp2(L2E * e[i]);
    };

    auto procN = [&](int k, auto nstc){
        constexpr int NST = decltype(nstc)::value;
        const float* db = dsc + (k & 1)*256 + 4*h;
        #pragma unroll
        for (int i = 0; i < NST; i++){
            accu acc;
            acc.c = __builtin_amdgcn_mfma_f32_32x32x16_bf16(
                        A0f, __builtin_bit_cast(bfrag, B0v), zacc, 0, 0, 0);
            acc.c = __builtin_amdgcn_mfma_f32_32x32x16_bf16(
                        A1f, __builtin_bit_cast(bfrag, B1v), acc.c, 0, 0, 0);

            // D_t row scales: broadcast LDS reads (rows per reg-quad contiguous)
            const f32x2* d0 = (const f32x2*)(db + i*32 +  0);
            const f32x2* d1 = (const f32x2*)(db + i*32 +  8);
            const f32x2* d2 = (const f32x2*)(db + i*32 + 16);
            const f32x2* d3 = (const f32x2*)(db + i*32 + 24);
            acc.p[0] *= d0[0]; acc.p[1] *= d0[1];
            acc.p[2] *= d1[0]; acc.p[3] *= d1[1];
            acc.p[4] *= d2[0]; acc.p[5] *= d2[1];
            acc.p[6] *= d3[0]; acc.p[7] *= d3[1];

            // per-column renorm every 8 steps: exact power-of-2 via exponent bits.
            // acc[0] (row 4h) is within ~2^11 of the column max -> safe scale ref.
            if (i == 7){
                float x  = acc.c[0];
                float xo = __shfl_xor(x, 32, 64);
                float xs = h ? xo : x;                 // both halves use h=0's value
                u32 xb = __builtin_bit_cast(u32, xs);
                int ex = (int)((xb >> 23) & 0xFFu);
                ex = ex < 24 ? 24 : (ex > 230 ? 230 : ex);
                off += (float)(ex - 127);
                f32x2 s2;
                s2.x = s2.y = __builtin_bit_cast(float, (u32)(254 - ex) << 23);
                #pragma unroll
                for (int q = 0; q < 8; q++) acc.p[q] *= s2;
            }

            // pack C/D -> bf16, half-swap into B-operand layout
            u32 P0 = pkbf(acc.c[0],  acc.c[1]),  P1 = pkbf(acc.c[2],  acc.c[3]);
            u32 P2 = pkbf(acc.c[4],  acc.c[5]),  P3 = pkbf(acc.c[6],  acc.c[7]);
            u32 P4 = pkbf(acc.c[8],  acc.c[9]),  P5 = pkbf(acc.c[10], acc.c[11]);
            u32 P6 = pkbf(acc.c[12], acc.c[13]), P7 = pkbf(acc.c[14], acc.c[15]);
            half_swap(P0, P2, h); half_swap(P1, P3, h);
            half_swap(P4, P6, h); half_swap(P5, P7, h);
            B0v[0]=P0; B0v[1]=P1; B0v[2]=P2; B0v[3]=P3;
            B1v[0]=P4; B1v[1]=P5; B1v[2]=P6; B1v[3]=P7;
        }
    };

    issue(eA, 0); commit(eA, 0);
    #pragma unroll 1
    for (int k = 0; k < 14; k += 2){
        issue(eB, k + 1);
        procN(k, ic<8>{});
        commit(eB, k + 1);
        issue(eA, k + 2);
        procN(k + 1, ic<8>{});
        commit(eA, k + 2);
    }
    issue(eB, 15);
    procN(14, ic<8>{});
    commit(eB, 15);
    if (c != 7) procN(15, ic<8>{});     // wave-uniform branch
    else        procN(15, ic<7>{});     // chunk 7 has 127 steps

    // store MT in B-frag form: wmat[bc*512 + d*64 + lane]
    const size_t mb = (size_t)bc * 512;
    #pragma unroll
    for (int d = 0; d < 4; d++){
        wmat[mb + d*64 + lt]     = B0v[d];
        wmat[mb + (4+d)*64 + lt] = B1v[d];
    }
    if (h == 0) woff[bc*32 + m] = off;
}

// ---------------- Phase 2: per-batch combine + full gold score ----------------
__global__ __launch_bounds__(64) void crf_combine(
    const float* __restrict__ logits, const float* __restrict__ trans,
    const int* __restrict__ tags, const int* __restrict__ lens,
    const u32* __restrict__ wmat, const float* __restrict__ woff,
    float* __restrict__ out)
{
    __shared__ __align__(16) float ldsT[NT*NT];
    __shared__ __align__(16) int   ldsTag[NS];
    __shared__ __align__(16) float ldsU[NT];

    const int tid = threadIdx.x;
    const int m   = tid & 31;
    const int b   = blockIdx.x;
    const int len = lens[b];
    const float* lgb = logits + (size_t)b * NS * NT;

    #pragma unroll
    for (int i = 0; i < 16; i++) ldsT[tid + i*64] = trans[tid + i*64];
    const int4* tg4 = (const int4*)(tags + b*NS);
    #pragma unroll
    for (int i = 0; i < 4; i++) ((int4*)ldsTag)[tid + i*64] = tg4[tid + i*64];
    __syncthreads();

    // gold: emissions (gathered) + transitions
    float g = 0.0f;
    #pragma unroll
    for (int it = 0; it < 16; it++){
        int t = tid + it*64;
        if (t < len){
            int tg = ldsTag[t];
            g += lgb[t*NT + tg];
            if (t >= 1) g += ldsT[ldsTag[t-1]*NT + tg];
        }
    }

    // v init = exp(emit_0), combine 8 chunk matrices in log-scaled space
    float v = fexp2(L2E * lgb[m]);
    float voff = 0.0f;

    const int n  = m;
    const int f  = n >> 4;
    const int hh = (n >> 3) & 1;
    const int di = f*4 + ((n >> 1) & 3);    // stored dword index holding row k=n

    for (int cc = 0; cc < 8; cc++){
        const int bcn = b*8 + cc;
        float offm = woff[bcn*32 + m];
        float w = flog2(v) + offm;          // per-element log2 magnitude
        float mw = w;
        #pragma unroll
        for (int d = 1; d <= 16; d <<= 1) mw = fmaxf(mw, __shfl_xor(mw, d, 64));
        float u = fexp2(w - mw);
        if (tid < 32) ldsU[m] = u;
        __syncthreads();

        const uint4* mp = (const uint4*)(wmat + (size_t)bcn*512 + di*64 + hh*32);
        float acc = 0.0f;
        #pragma unroll
        for (int qq = 0; qq < 8; qq++){
            uint4  md = mp[qq];
            float4 uu = ((const float4*)ldsU)[qq];
            float e0 = __builtin_bit_cast(float, (n&1) ? (md.x & 0xFFFF0000u) : (md.x << 16));
            float e1 = __builtin_bit_cast(float, (n&1) ? (md.y & 0xFFFF0000u) : (md.y << 16));
            float e2 = __builtin_bit_cast(float, (n&1) ? (md.z & 0xFFFF0000u) : (md.z << 16));
            float e3 = __builtin_bit_cast(float, (n&1) ? (md.w & 0xFFFF0000u) : (md.w << 16));
            acc = fmaf(e0, uu.x, acc);
            acc = fmaf(e1, uu.y, acc);
            acc = fmaf(e2, uu.z, acc);
            acc = fmaf(e3, uu.w, acc);
        }
        v = acc;
        voff += mw;
        __syncthreads();
    }

    float s = v;
    #pragma unroll
    for (int d = 1; d <= 16; d <<= 1) s += __shfl_xor(s, d, 64);   // sum over 32 tags
    #pragma unroll
    for (int d = 1; d <= 32; d <<= 1) g += __shfl_xor(g, d, 64);   // sum over 64 lanes
    if (tid == 0){
        float logz = LN2 * (voff + flog2(s));
        atomicAdd(out, (logz - g) * (1.0f / (float)NB));
    }
}

extern "C" void kernel_launch(void* const* d_in, const int* in_sizes, int n_in,
                              void* d_out, int out_size, void* d_ws, size_t ws_size,
                              hipStream_t stream) {
    const float* logits = (const float*)d_in[0];
    const float* trans  = (const float*)d_in[1];
    const int*   tags   = (const int*)d_in[2];
    const int*   lens   = (const int*)d_in[3];

    u32*   wmat = (u32*)d_ws;                        // 8192*512*4 = 16 MB
    float* woff = (float*)(wmat + 8192*512);         // 8192*32 floats = 1 MB

    hipMemsetAsync(d_out, 0, sizeof(float), stream);
    crf_chunk  <<<2048, 256, 0, stream>>>(logits, trans, wmat, woff);
    crf_combine<<<1024, 64, 0, stream>>>(logits, trans, tags, lens, wmat, woff,
                                         (float*)d_out);
}

// Round 5
// 263.726 us; speedup vs baseline: 1.5162x; 1.0120x over previous
//
#include <hip/hip_runtime.h>

#define NB 1024
#define NS 1024
#define NT 32
#define L2E 1.44269504088896340736f
#define LN2 0.69314718055994530942f

typedef short        bfrag  __attribute__((ext_vector_type(8)));   // 8 bf16 (4 VGPR)
typedef float        cfrag  __attribute__((ext_vector_type(16)));  // 16 f32 acc
typedef __bf16       bf16x2 __attribute__((ext_vector_type(2)));
typedef float        f32x8  __attribute__((ext_vector_type(8)));
typedef float        f32x4  __attribute__((ext_vector_type(4)));
typedef float        f32x2  __attribute__((ext_vector_type(2)));
typedef unsigned int u32;
typedef unsigned int u32x2v __attribute__((ext_vector_type(2)));
typedef unsigned int u32x4  __attribute__((ext_vector_type(4)));

__device__ __forceinline__ float fexp2(float x){ return __builtin_amdgcn_exp2f(x); }
__device__ __forceinline__ float flog2(float x){ return __builtin_amdgcn_logf(x); }

// RNE pack (prologue only — may be multi-inst, don't care there)
__device__ __forceinline__ u32 pkbf_rne(float a, float b){
    f32x2 t; t.x = a; t.y = b;
    return __builtin_bit_cast(u32, __builtin_convertvector(t, bf16x2));
}
// truncation pack: single v_perm_b32. low16 = bf16_trunc(a), high16 = bf16_trunc(b).
// v_perm byte indices: 0-3 from S1 (=a), 4-7 from S0 (=b); want [b.3,b.2,a.3,a.2].
__device__ __forceinline__ u32 pkbf_t(float a, float b){
    return __builtin_amdgcn_perm(__builtin_bit_cast(u32, b),
                                 __builtin_bit_cast(u32, a), 0x07060302u);
}
__device__ __forceinline__ bfrag mk_afrag(f32x8 v){
    u32x4 r;
    r[0] = pkbf_rne(v[0], v[1]); r[1] = pkbf_rne(v[2], v[3]);
    r[2] = pkbf_rne(v[4], v[5]); r[3] = pkbf_rne(v[6], v[7]);
    return __builtin_bit_cast(bfrag, r);
}

#if __has_builtin(__builtin_amdgcn_permlane32_swap)
#define HAVE_PLSWAP 1
#else
#define HAVE_PLSWAP 0
#endif

// after call: x_new = {x.lo32, y.lo32}, y_new = {x.hi32, y.hi32}
__device__ __forceinline__ void half_swap(u32 &x, u32 &y, int h){
#if HAVE_PLSWAP
    u32x2v r = __builtin_amdgcn_permlane32_swap(x, y, false, false);
    x = r[0]; y = r[1];
#else
    u32 X  = __shfl_xor(h ? x : y, 32, 64);
    u32 nx = h ? X : x;
    u32 ny = h ? y : X;
    x = nx; y = ny;
#endif
}

template<int N> struct ic { static constexpr int value = N; };
union accu { cfrag c; f32x2 p[8]; };
union q4u  { f32x4 v; f32x2 p[2]; };

// ---------------- Phase 1: per-(batch,chunk) 32x32 transfer matrix ----------------
// 4 independent chunk-waves per 256-thread block. M <- D_t * (E^T @ M); constant
// bf16 A; D via broadcast ds_read_b128; truncation bf16 pack (1 v_perm each);
// wave-uniform power-of-2 renorm: mid-block applied in place, end-of-block folded
// into the next block's staged exp2 (free). woff is one scalar per chunk.
__global__ __launch_bounds__(256, 8) void crf_chunk(
    const float* __restrict__ logits, const float* __restrict__ trans,
    u32* __restrict__ wmat, float* __restrict__ woff)
{
    __shared__ __align__(16) float dscall[4 * 512];   // per-wave: 2 bufs x 8 steps x 32

    const int tid = threadIdx.x;
    const int wv  = tid >> 6, lt = tid & 63;
    const int m   = lt & 31,  h  = lt >> 5;
    const int bc  = blockIdx.x * 4 + wv;
    const int b   = bc >> 3,  c  = bc & 7;
    float* dsc = dscall + wv * 512;

    const float* base = logits + (size_t)b * NS * NT;

    // constant A frags: Et[m][k] = exp(trans[k][m]); MFMA#1 k=8h+j, MFMA#2 k=16+8h+j
    f32x8 Et0, Et1;
    #pragma unroll
    for (int j = 0; j < 8; j++){
        Et0[j] = fexp2(L2E * trans[(     8*h + j)*NT + m]);
        Et1[j] = fexp2(L2E * trans[(16 + 8*h + j)*NT + m]);
    }
    const bfrag A0f = mk_afrag(Et0);
    const bfrag A1f = mk_afrag(Et1);

    // B = identity (packed bf16): B[k][n], n=lane&31, dword d covers k = 16f+8h+2d(+1)
    u32x4 B0v, B1v;
    #pragma unroll
    for (int d = 0; d < 4; d++){
        int k0 = 8*h + 2*d;      u32 v = 0;
        if (k0     == m) v |= 0x3F80u;
        if (k0 + 1 == m) v |= 0x3F800000u;
        B0v[d] = v;
        int k1 = 16 + 8*h + 2*d; v = 0;
        if (k1     == m) v |= 0x3F80u;
        if (k1 + 1 == m) v |= 0x3F800000u;
        B1v[d] = v;
    }

    cfrag zacc;
    #pragma unroll
    for (int q = 0; q < 16; q++) zacc[q] = 0.0f;

    int   offi = 0;        // accumulated log2 scale (integer, wave-uniform)
    float exf  = 0.0f;     // deferred scale to fold into next block's step-0 D
    const int tbeg = c*128 + 1;

    float eA[4], eB[4];

    auto issue = [&](float (&e)[4], int k){
        const int t0 = tbeg + k*8 + 4*h;
        #pragma unroll
        for (int i = 0; i < 4; i++){
            int t = t0 + i; t = t > (NS-1) ? (NS-1) : t;   // clamp c==7 tail
            e[i] = base[t*NT + m];
        }
    };
    // stage d = exp2(L2E*e); half h==0 stages step 0 of the block and carries the
    // deferred wave-uniform renorm (-exf) — scalar scale commutes with the product.
    auto commit = [&](float (&e)[4], int k){
        float* sp = dsc + (k & 1)*256 + (4*h)*32 + m;
        float a0 = (h == 0) ? -exf : 0.0f;
        sp[0]    = fexp2(fmaf(L2E, e[0], a0));
        sp[32]   = fexp2(L2E * e[1]);
        sp[64]   = fexp2(L2E * e[2]);
        sp[96]   = fexp2(L2E * e[3]);
    };

    auto exref = [&](float ref)->int{
        u32 xb = __builtin_bit_cast(u32, ref);
        u32 xf = __builtin_amdgcn_readfirstlane(xb);
        int ex = (int)((xf >> 23) & 0xFFu) - 127;
        return ex < -120 ? -120 : (ex > 120 ? 120 : ex);
    };

    auto procN = [&](int k, bool defer, auto nstc){
        constexpr int NST = decltype(nstc)::value;
        const float* db = dsc + (k & 1)*256 + 4*h;
        #pragma unroll
        for (int i = 0; i < NST; i++){
            accu acc;
            acc.c = __builtin_amdgcn_mfma_f32_32x32x16_bf16(
                        A0f, __builtin_bit_cast(bfrag, B0v), zacc, 0, 0, 0);
            acc.c = __builtin_amdgcn_mfma_f32_32x32x16_bf16(
                        A1f, __builtin_bit_cast(bfrag, B1v), acc.c, 0, 0, 0);

            // D_t row scales: 4 broadcast b128 reads, 8 pk_mul
            q4u d0, d1, d2, d3;
            d0.v = *(const f32x4*)(db + i*32 +  0);
            d1.v = *(const f32x4*)(db + i*32 +  8);
            d2.v = *(const f32x4*)(db + i*32 + 16);
            d3.v = *(const f32x4*)(db + i*32 + 24);
            acc.p[0] *= d0.p[0]; acc.p[1] *= d0.p[1];
            acc.p[2] *= d1.p[0]; acc.p[3] *= d1.p[1];
            acc.p[4] *= d2.p[0]; acc.p[5] *= d2.p[1];
            acc.p[6] *= d3.p[0]; acc.p[7] *= d3.p[1];

            // mid-block in-place renorm (range safety, power of 2, wave-uniform)
            if (i == 3){
                int ex = exref(fmaxf(acc.c[0], acc.c[8]));
                offi += ex;
                f32x2 s2;
                s2.x = s2.y = __builtin_bit_cast(float, (u32)(127 - ex) << 23);
                #pragma unroll
                for (int q = 0; q < 8; q++) acc.p[q] *= s2;
            }
            // end-of-block renorm: record only; applied via next commit (free)
            if (i == 7 && defer){
                int ex = exref(fmaxf(acc.c[0], acc.c[8]));
                offi += ex;
                exf = (float)ex;
            }

            // pack C/D -> bf16 (truncation, 1 v_perm each), half-swap to B layout
            u32 P0 = pkbf_t(acc.c[0],  acc.c[1]),  P1 = pkbf_t(acc.c[2],  acc.c[3]);
            u32 P2 = pkbf_t(acc.c[4],  acc.c[5]),  P3 = pkbf_t(acc.c[6],  acc.c[7]);
            u32 P4 = pkbf_t(acc.c[8],  acc.c[9]),  P5 = pkbf_t(acc.c[10], acc.c[11]);
            u32 P6 = pkbf_t(acc.c[12], acc.c[13]), P7 = pkbf_t(acc.c[14], acc.c[15]);
            half_swap(P0, P2, h); half_swap(P1, P3, h);
            half_swap(P4, P6, h); half_swap(P5, P7, h);
            B0v[0]=P0; B0v[1]=P1; B0v[2]=P2; B0v[3]=P3;
            B1v[0]=P4; B1v[1]=P5; B1v[2]=P6; B1v[3]=P7;
        }
    };

    issue(eA, 0); commit(eA, 0);
    #pragma unroll 1
    for (int k = 0; k < 14; k += 2){
        issue(eB, k + 1);
        procN(k, true, ic<8>{});
        commit(eB, k + 1);
        issue(eA, k + 2);
        procN(k + 1, true, ic<8>{});
        commit(eA, k + 2);
    }
    issue(eB, 15);
    procN(14, true, ic<8>{});
    commit(eB, 15);
    if (c != 7) procN(15, false, ic<8>{});   // wave-uniform branch
    else        procN(15, false, ic<7>{});   // chunk 7 has 127 steps

    // store MT in B-frag form: wmat[bc*512 + d*64 + lane]
    const size_t mb = (size_t)bc * 512;
    #pragma unroll
    for (int d = 0; d < 4; d++){
        wmat[mb + d*64 + lt]     = B0v[d];
        wmat[mb + (4+d)*64 + lt] = B1v[d];
    }
    if (lt == 0) woff[bc] = (float)offi;
}

// ---------------- Phase 2: per-batch combine + full gold score ----------------
__global__ __launch_bounds__(64) void crf_combine(
    const float* __restrict__ logits, const float* __restrict__ trans,
    const int* __restrict__ tags, const int* __restrict__ lens,
    const u32* __restrict__ wmat, const float* __restrict__ woff,
    float* __restrict__ out)
{
    __shared__ __align__(16) float ldsT[NT*NT];
    __shared__ __align__(16) int   ldsTag[NS];
    __shared__ __align__(16) float ldsU[NT];

    const int tid = threadIdx.x;
    const int m   = tid & 31;
    const int b   = blockIdx.x;
    const int len = lens[b];
    const float* lgb = logits + (size_t)b * NS * NT;

    #pragma unroll
    for (int i = 0; i < 16; i++) ldsT[tid + i*64] = trans[tid + i*64];
    const int4* tg4 = (const int4*)(tags + b*NS);
    #pragma unroll
    for (int i = 0; i < 4; i++) ((int4*)ldsTag)[tid + i*64] = tg4[tid + i*64];
    __syncthreads();

    // gold: emissions (gathered) + transitions
    float g = 0.0f;
    #pragma unroll
    for (int it = 0; it < 16; it++){
        int t = tid + it*64;
        if (t < len){
            int tg = ldsTag[t];
            g += lgb[t*NT + tg];
            if (t >= 1) g += ldsT[ldsTag[t-1]*NT + tg];
        }
    }

    // v init = exp(emit_0), combine 8 chunk matrices in log-scaled space
    float v = fexp2(L2E * lgb[m]);
    float voff = 0.0f;

    const int n  = m;
    const int f  = n >> 4;
    const int hh = (n >> 3) & 1;
    const int di = f*4 + ((n >> 1) & 3);    // stored dword index holding row k=n

    for (int cc = 0; cc < 8; cc++){
        const int bcn = b*8 + cc;
        float offc = woff[bcn];             // wave-uniform chunk scale
        float w = flog2(v) + offc;          // per-element log2 magnitude
        float mw = w;
        #pragma unroll
        for (int d = 1; d <= 16; d <<= 1) mw = fmaxf(mw, __shfl_xor(mw, d, 64));
        float u = fexp2(w - mw);
        if (tid < 32) ldsU[m] = u;
        __syncthreads();

        const uint4* mp = (const uint4*)(wmat + (size_t)bcn*512 + di*64 + hh*32);
        float acc = 0.0f;
        #pragma unroll
        for (int qq = 0; qq < 8; qq++){
            uint4  md = mp[qq];
            float4 uu = ((const float4*)ldsU)[qq];
            float e0 = __builtin_bit_cast(float, (n&1) ? (md.x & 0xFFFF0000u) : (md.x << 16));
            float e1 = __builtin_bit_cast(float, (n&1) ? (md.y & 0xFFFF0000u) : (md.y << 16));
            float e2 = __builtin_bit_cast(float, (n&1) ? (md.z & 0xFFFF0000u) : (md.z << 16));
            float e3 = __builtin_bit_cast(float, (n&1) ? (md.w & 0xFFFF0000u) : (md.w << 16));
            acc = fmaf(e0, uu.x, acc);
            acc = fmaf(e1, uu.y, acc);
            acc = fmaf(e2, uu.z, acc);
            acc = fmaf(e3, uu.w, acc);
        }
        v = acc;
        voff += mw;
        __syncthreads();
    }

    float s = v;
    #pragma unroll
    for (int d = 1; d <= 16; d <<= 1) s += __shfl_xor(s, d, 64);   // sum over 32 tags
    #pragma unroll
    for (int d = 1; d <= 32; d <<= 1) g += __shfl_xor(g, d, 64);   // sum over 64 lanes
    if (tid == 0){
        float logz = LN2 * (voff + flog2(s));
        atomicAdd(out, (logz - g) * (1.0f / (float)NB));
    }
}

extern "C" void kernel_launch(void* const* d_in, const int* in_sizes, int n_in,
                              void* d_out, int out_size, void* d_ws, size_t ws_size,
                              hipStream_t stream) {
    const float* logits = (const float*)d_in[0];
    const float* trans  = (const float*)d_in[1];
    const int*   tags   = (const int*)d_in[2];
    const int*   lens   = (const int*)d_in[3];

    u32*   wmat = (u32*)d_ws;                        // 8192*512*4 = 16 MB
    float* woff = (float*)(wmat + 8192*512);         // 8192 floats

    hipMemsetAsync(d_out, 0, sizeof(float), stream);
    crf_chunk  <<<2048, 256, 0, stream>>>(logits, trans, wmat, woff);
    crf_combine<<<1024, 64, 0, stream>>>(logits, trans, tags, lens, wmat, woff,
                                         (float*)d_out);
}